// Round 1
// baseline (2561.258 us; speedup 1.0000x reference)
//
#include <hip/hip_runtime.h>
#include <cstdint>
#include <cstddef>

__device__ __forceinline__ float lrelu(float v) { return v >= 0.0f ? v : 0.01f * v; }
__device__ __forceinline__ float fsigmoid(float x) {
  x = fminf(fmaxf(x, -30.0f), 30.0f);
  return 1.0f / (1.0f + __expf(-x));
}
__device__ __forceinline__ float ftanh(float x) {
  x = fminf(fmaxf(x, -15.0f), 15.0f);
  float e = __expf(2.0f * x);
  return (e - 1.0f) / (e + 1.0f);
}

// ---------------- degree / norm / CSR build ----------------
__global__ void k_deg(const int* __restrict__ dst, int* __restrict__ indeg, int E) {
  int e = blockIdx.x * 256 + threadIdx.x;
  if (e < E) atomicAdd(&indeg[dst[e]], 1);
}

__global__ void k_dis(const int* __restrict__ indeg, float* __restrict__ dis, int n) {
  int i = blockIdx.x * 256 + threadIdx.x;
  if (i < n) dis[i] = rsqrtf((float)(indeg[i] + 1));  // +1 self-loop; deg>=1 always
}

__global__ __launch_bounds__(1024) void k_scan(const int* __restrict__ v, int* __restrict__ rp, int n) {
  __shared__ int wsum[16];
  int t = threadIdx.x;
  int lane = t & 63, wv = t >> 6;
  int running = 0;
  for (int base = 0; base < n; base += 1024) {
    int val = (base + t < n) ? v[base + t] : 0;
    int s = val;
    #pragma unroll
    for (int off = 1; off < 64; off <<= 1) {
      int u = __shfl_up(s, off);
      if (lane >= off) s += u;
    }
    if (lane == 63) wsum[wv] = s;
    __syncthreads();
    int wadd = 0;
    for (int w = 0; w < wv; ++w) wadd += wsum[w];
    if (base + t < n) rp[base + t] = running + wadd + s - val;  // exclusive
    int tot = 0;
    #pragma unroll
    for (int w = 0; w < 16; ++w) tot += wsum[w];
    running += tot;
    __syncthreads();
  }
  if (t == 0) rp[n] = running;
}

__global__ void k_fill(const int* __restrict__ src, const int* __restrict__ dst,
                       const float* __restrict__ dis, int* __restrict__ cursor,
                       int* __restrict__ csrc, float* __restrict__ cw, int E) {
  int e = blockIdx.x * 256 + threadIdx.x;
  if (e >= E) return;
  int s = src[e], d = dst[e];
  int pos = atomicAdd(&cursor[d], 1);
  csrc[pos] = s;
  cw[pos] = dis[s] * dis[d];
}

// ---------------- generic fp32 GEMM: C = act(A[M,K] @ B[K,Nc] + bias) ----------------
// 64x64 tile, 256 threads, 4x4 per thread, KC=32
template<int ACT, int BIAS>
__global__ __launch_bounds__(256) void k_gemm(const float* __restrict__ A, const float* __restrict__ B,
                                              const float* __restrict__ bias, float* __restrict__ C,
                                              int M, int K, int Nc) {
  __shared__ __align__(16) float As[32][68];  // As[k][m], padded stride (16B aligned, fewer write conflicts)
  __shared__ __align__(16) float Bs[32][64];  // Bs[k][n]
  const int bm = blockIdx.x * 64;
  const int bn = blockIdx.y * 64;
  const int tid = threadIdx.x;
  const int tr = tid & 15;    // row group (4 rows)
  const int tc = tid >> 4;    // col group (4 cols)
  const int arow = tid >> 2;  // 0..63
  const int aq = tid & 3;
  const int bk = tid >> 4;    // 0..15
  const int bc4 = tid & 15;
  float acc[4][4] = {};
  const bool avalid = (bm + arow) < M;
  const float* aptr = A + (size_t)(bm + arow) * K;

  for (int k0 = 0; k0 < K; k0 += 32) {
    #pragma unroll
    for (int it = 0; it < 2; ++it) {
      int q = aq + it * 4;
      float4 av = avalid ? *(const float4*)(aptr + k0 + q * 4) : make_float4(0.f, 0.f, 0.f, 0.f);
      As[q * 4 + 0][arow] = av.x;
      As[q * 4 + 1][arow] = av.y;
      As[q * 4 + 2][arow] = av.z;
      As[q * 4 + 3][arow] = av.w;
    }
    #pragma unroll
    for (int it = 0; it < 2; ++it) {
      int k = bk + it * 16;
      *(float4*)&Bs[k][bc4 * 4] = *(const float4*)(B + (size_t)(k0 + k) * Nc + bn + bc4 * 4);
    }
    __syncthreads();
    #pragma unroll
    for (int k = 0; k < 32; ++k) {
      float4 a4 = *(const float4*)&As[k][tr * 4];
      float4 b4 = *(const float4*)&Bs[k][tc * 4];
      float av[4] = {a4.x, a4.y, a4.z, a4.w};
      float bv[4] = {b4.x, b4.y, b4.z, b4.w};
      #pragma unroll
      for (int i = 0; i < 4; ++i)
        #pragma unroll
        for (int j = 0; j < 4; ++j)
          acc[i][j] = fmaf(av[i], bv[j], acc[i][j]);
    }
    __syncthreads();
  }
  float bb[4] = {0.f, 0.f, 0.f, 0.f};
  if (BIAS) {
    float4 b4 = *(const float4*)(bias + bn + tc * 4);
    bb[0] = b4.x; bb[1] = b4.y; bb[2] = b4.z; bb[3] = b4.w;
  }
  #pragma unroll
  for (int i = 0; i < 4; ++i) {
    int m = bm + tr * 4 + i;
    if (m >= M) continue;
    float o[4];
    #pragma unroll
    for (int j = 0; j < 4; ++j) {
      float v = acc[i][j] + bb[j];
      o[j] = ACT ? lrelu(v) : v;
    }
    *(float4*)(C + (size_t)m * Nc + bn + tc * 4) = make_float4(o[0], o[1], o[2], o[3]);
  }
}

// ---------------- CSR aggregation: out[n] = leaky(sum_{e: dst=n} w_e*hw[src_e] + dis[n]^2*hw[n] + bias) ----------------
template<int F>
__global__ __launch_bounds__(256) void k_agg(const float* __restrict__ hw, const int* __restrict__ rp,
                                             const int* __restrict__ csrc, const float* __restrict__ cw,
                                             const float* __restrict__ dis, const float* __restrict__ bias,
                                             float* __restrict__ outp, int M) {
  int gw = (int)((blockIdx.x * 256 + threadIdx.x) >> 6);  // one wave per node
  int lane = threadIdx.x & 63;
  if (gw >= M) return;
  constexpr int V = F / 64;  // 4 (F=256) or 2 (F=128)
  float acc[V];
  float dn = dis[gw];
  float sw = dn * dn;
  {
    const float* p = hw + (size_t)gw * F + lane * V;
    if constexpr (V == 4) {
      float4 t = *(const float4*)p;
      acc[0] = t.x * sw; acc[1] = t.y * sw; acc[2] = t.z * sw; acc[3] = t.w * sw;
    } else {
      float2 t = *(const float2*)p;
      acc[0] = t.x * sw; acc[1] = t.y * sw;
    }
  }
  int e0 = rp[gw], e1 = rp[gw + 1];
  for (int e = e0; e < e1; ++e) {
    int s = csrc[e];
    float w = cw[e];
    const float* p = hw + (size_t)s * F + lane * V;
    if constexpr (V == 4) {
      float4 t = *(const float4*)p;
      acc[0] = fmaf(w, t.x, acc[0]); acc[1] = fmaf(w, t.y, acc[1]);
      acc[2] = fmaf(w, t.z, acc[2]); acc[3] = fmaf(w, t.w, acc[3]);
    } else {
      float2 t = *(const float2*)p;
      acc[0] = fmaf(w, t.x, acc[0]); acc[1] = fmaf(w, t.y, acc[1]);
    }
  }
  const float* bp = bias + lane * V;
  if constexpr (V == 4) {
    float4 b4 = *(const float4*)bp;
    *(float4*)(outp + (size_t)gw * F + lane * 4) =
        make_float4(lrelu(acc[0] + b4.x), lrelu(acc[1] + b4.y), lrelu(acc[2] + b4.z), lrelu(acc[3] + b4.w));
  } else {
    float2 b2 = *(const float2*)bp;
    *(float2*)(outp + (size_t)gw * F + lane * 2) = make_float2(lrelu(acc[0] + b2.x), lrelu(acc[1] + b2.y));
  }
}

// ---------------- fused GRU cell: out = GRUCell(xt, hp) ----------------
// block: 64 rows x 64 H-cols; 6 simultaneous GEMM accumulations (ir,iz,in,hr,hz,hn); KC=16
template<int HD, int KD>
__global__ __launch_bounds__(256) void k_gru(const float* __restrict__ xt, const float* __restrict__ hp,
                                             const float* __restrict__ Wih, const float* __restrict__ Whh,
                                             const float* __restrict__ bih, const float* __restrict__ bhh,
                                             float* __restrict__ out, int M) {
  __shared__ __align__(16) float xs[16][68];
  __shared__ __align__(16) float hs[16][68];
  __shared__ __align__(16) float ws[6][16][68];
  const int bm = blockIdx.x * 64;
  const int c0 = blockIdx.y * 64;
  const int tid = threadIdx.x;
  const int tr = tid & 15;
  const int tc = tid >> 4;
  const int arow = tid >> 2;  // 0..63
  const int aq = tid & 3;     // k-quad 0..3
  float acc[6][4][4] = {};
  const bool avalid = (bm + arow) < M;
  const float* xp = xt + (size_t)(bm + arow) * KD;
  const float* hpp = hp + (size_t)(bm + arow) * KD;

  for (int k0 = 0; k0 < KD; k0 += 16) {
    {
      float4 av = avalid ? *(const float4*)(xp + k0 + aq * 4) : make_float4(0.f, 0.f, 0.f, 0.f);
      xs[aq * 4 + 0][arow] = av.x; xs[aq * 4 + 1][arow] = av.y;
      xs[aq * 4 + 2][arow] = av.z; xs[aq * 4 + 3][arow] = av.w;
      float4 hv = avalid ? *(const float4*)(hpp + k0 + aq * 4) : make_float4(0.f, 0.f, 0.f, 0.f);
      hs[aq * 4 + 0][arow] = hv.x; hs[aq * 4 + 1][arow] = hv.y;
      hs[aq * 4 + 2][arow] = hv.z; hs[aq * 4 + 3][arow] = hv.w;
    }
    #pragma unroll
    for (int s = 0; s < 6; ++s) {
      const float* W = (s < 3) ? Wih : Whh;
      int g = (s < 3) ? s : s - 3;
      float4 wv = *(const float4*)(W + (size_t)(g * HD + c0 + arow) * KD + k0 + aq * 4);
      ws[s][aq * 4 + 0][arow] = wv.x; ws[s][aq * 4 + 1][arow] = wv.y;
      ws[s][aq * 4 + 2][arow] = wv.z; ws[s][aq * 4 + 3][arow] = wv.w;
    }
    __syncthreads();
    #pragma unroll
    for (int k = 0; k < 16; ++k) {
      float4 x4 = *(const float4*)&xs[k][tr * 4];
      float4 h4 = *(const float4*)&hs[k][tr * 4];
      float xv[4] = {x4.x, x4.y, x4.z, x4.w};
      float hv[4] = {h4.x, h4.y, h4.z, h4.w};
      #pragma unroll
      for (int s = 0; s < 6; ++s) {
        float4 w4 = *(const float4*)&ws[s][k][tc * 4];
        float wv[4] = {w4.x, w4.y, w4.z, w4.w};
        #pragma unroll
        for (int i = 0; i < 4; ++i) {
          float a = (s < 3) ? xv[i] : hv[i];
          #pragma unroll
          for (int j = 0; j < 4; ++j) acc[s][i][j] = fmaf(a, wv[j], acc[s][i][j]);
        }
      }
    }
    __syncthreads();
  }
  const int cb = c0 + tc * 4;
  float bi[3][4], bh[3][4];
  #pragma unroll
  for (int g = 0; g < 3; ++g)
    #pragma unroll
    for (int j = 0; j < 4; ++j) {
      bi[g][j] = bih[g * HD + cb + j];
      bh[g][j] = bhh[g * HD + cb + j];
    }
  #pragma unroll
  for (int i = 0; i < 4; ++i) {
    int m = bm + tr * 4 + i;
    if (m >= M) continue;
    float4 hp4 = *(const float4*)(hp + (size_t)m * HD + cb);
    float hpv[4] = {hp4.x, hp4.y, hp4.z, hp4.w};
    float o[4];
    #pragma unroll
    for (int j = 0; j < 4; ++j) {
      float r = fsigmoid(acc[0][i][j] + bi[0][j] + acc[3][i][j] + bh[0][j]);
      float z = fsigmoid(acc[1][i][j] + bi[1][j] + acc[4][i][j] + bh[1][j]);
      float nv = ftanh(acc[2][i][j] + bi[2][j] + r * (acc[5][i][j] + bh[2][j]));
      o[j] = (1.0f - z) * nv + z * hpv[j];
    }
    *(float4*)(out + (size_t)m * HD + cb) = make_float4(o[0], o[1], o[2], o[3]);
  }
}

// ---------------- post head: out[n] = sum_cols(emb1 @ Wpost + bpost) ----------------
__global__ __launch_bounds__(256) void k_post(const float* __restrict__ emb, const float* __restrict__ Wpost,
                                              const float* __restrict__ bpost, float* __restrict__ outv, int M) {
  int gw = (int)((blockIdx.x * 256 + threadIdx.x) >> 6);
  int lane = threadIdx.x & 63;
  if (gw >= M) return;
  float2 ev = *(const float2*)(emb + (size_t)gw * 128 + lane * 2);
  float4 wv = *(const float4*)(Wpost + lane * 4);  // rows 2*lane, 2*lane+1 of [128,2]
  float p = ev.x * (wv.x + wv.y) + ev.y * (wv.z + wv.w);
  #pragma unroll
  for (int o = 32; o > 0; o >>= 1) p += __shfl_xor(p, o);
  if (lane == 0) outv[gw] = p + bpost[0] + bpost[1];
}

extern "C" void kernel_launch(void* const* d_in, const int* in_sizes, int n_in,
                              void* d_out, int out_size, void* d_ws, size_t ws_size,
                              hipStream_t stream) {
  const float* x     = (const float*)d_in[0];
  const int*   ei    = (const int*)d_in[1];
  const float* prev0 = (const float*)d_in[2];
  const float* prev1 = (const float*)d_in[3];
  const float* Wp1   = (const float*)d_in[4];
  const float* bp1   = (const float*)d_in[5];
  const float* Wp2   = (const float*)d_in[6];
  const float* bp2   = (const float*)d_in[7];
  const float* Wc1   = (const float*)d_in[8];
  const float* bc1   = (const float*)d_in[9];
  const float* Wc2   = (const float*)d_in[10];
  const float* bc2   = (const float*)d_in[11];
  const float* Wih1  = (const float*)d_in[12];
  const float* Whh1  = (const float*)d_in[13];
  const float* bih1  = (const float*)d_in[14];
  const float* bhh1  = (const float*)d_in[15];
  const float* Wih2  = (const float*)d_in[16];
  const float* Whh2  = (const float*)d_in[17];
  const float* bih2  = (const float*)d_in[18];
  const float* bhh2  = (const float*)d_in[19];
  const float* Wpost = (const float*)d_in[20];
  const float* bpost = (const float*)d_in[21];

  const int N = in_sizes[0] / 128;   // 100000
  const int E = in_sizes[1] / 2;     // 1600000
  const int* srcp = ei;
  const int* dstp = ei + E;

  char* wsb = (char*)d_ws;
  size_t off = 0;
  auto alloc = [&](size_t bytes) -> void* {
    void* p = wsb + off;
    off = (off + bytes + 255) & ~(size_t)255;
    return p;
  };
  float* dis    = (float*)alloc((size_t)N * 4);
  int*   indeg  = (int*)alloc((size_t)N * 4);
  int*   rp     = (int*)alloc((size_t)(N + 1) * 4);
  int*   cursor = (int*)alloc((size_t)N * 4);
  int*   csrc   = (int*)alloc((size_t)E * 4);
  float* cw     = (float*)alloc((size_t)E * 4);
  float* bufA   = (float*)alloc((size_t)N * 256 * 4);  // h1 -> hw1
  float* bufB   = (float*)alloc((size_t)N * 128 * 4);  // hpre -> hw2
  float* bufC   = (float*)alloc((size_t)N * 256 * 4);  // gcn1 -> gcn2
  (void)ws_size; (void)n_in; (void)out_size;

  float* outv = (float*)d_out;
  float* emb0 = outv + N;
  float* emb1 = emb0 + (size_t)N * 256;

  // CSR build
  hipMemsetAsync(indeg, 0, (size_t)N * 4, stream);
  k_deg<<<(E + 255) / 256, 256, 0, stream>>>(dstp, indeg, E);
  k_dis<<<(N + 255) / 256, 256, 0, stream>>>(indeg, dis, N);
  k_scan<<<1, 1024, 0, stream>>>(indeg, rp, N);
  hipMemcpyAsync(cursor, rp, (size_t)N * 4, hipMemcpyDeviceToDevice, stream);
  k_fill<<<(E + 255) / 256, 256, 0, stream>>>(srcp, dstp, dis, cursor, csrc, cw, E);

  const int MB = (N + 63) / 64;
  // preprocess MLP
  k_gemm<1, 1><<<dim3(MB, 4), 256, 0, stream>>>(x, Wp1, bp1, bufA, N, 128, 256);
  k_gemm<1, 1><<<dim3(MB, 2), 256, 0, stream>>>(bufA, Wp2, bp2, bufB, N, 256, 128);
  // GCN1 + GRU1
  k_gemm<0, 0><<<dim3(MB, 4), 256, 0, stream>>>(bufB, Wc1, nullptr, bufA, N, 128, 256);
  k_agg<256><<<(N + 3) / 4, 256, 0, stream>>>(bufA, rp, csrc, cw, dis, bc1, bufC, N);
  k_gru<256, 256><<<dim3(MB, 4), 256, 0, stream>>>(bufC, prev0, Wih1, Whh1, bih1, bhh1, emb0, N);
  // GCN2 + GRU2
  k_gemm<0, 0><<<dim3(MB, 2), 256, 0, stream>>>(emb0, Wc2, nullptr, bufB, N, 256, 128);
  k_agg<128><<<(N + 3) / 4, 256, 0, stream>>>(bufB, rp, csrc, cw, dis, bc2, bufC, N);
  k_gru<128, 128><<<dim3(MB, 2), 256, 0, stream>>>(bufC, prev1, Wih2, Whh2, bih2, bhh2, emb1, N);
  // post head
  k_post<<<(N + 3) / 4, 256, 0, stream>>>(emb1, Wpost, bpost, outv, N);
}

// Round 2
// 1303.901 us; speedup vs baseline: 1.9643x; 1.9643x over previous
//
#include <hip/hip_runtime.h>
#include <cstdint>
#include <cstddef>

typedef __bf16 bf16x8 __attribute__((ext_vector_type(8)));
typedef float f32x4 __attribute__((ext_vector_type(4)));
typedef unsigned short us16;

__device__ __forceinline__ float lrelu(float v) { return v >= 0.0f ? v : 0.01f * v; }
__device__ __forceinline__ float fsigmoid(float x) {
  x = fminf(fmaxf(x, -30.0f), 30.0f);
  return 1.0f / (1.0f + __expf(-x));
}
__device__ __forceinline__ float ftanh(float x) {
  x = fminf(fmaxf(x, -15.0f), 15.0f);
  float e = __expf(2.0f * x);
  return (e - 1.0f) / (e + 1.0f);
}
__device__ __forceinline__ us16 f2b(float f) {
  unsigned int u = __builtin_bit_cast(unsigned int, f);
  u = (u + 0x7fffu + ((u >> 16) & 1u)) >> 16;
  return (us16)u;
}
__device__ __forceinline__ float b2f(us16 h) {
  unsigned int u = ((unsigned int)h) << 16;
  return __builtin_bit_cast(float, u);
}

// ---------------- degree / norm / CSR build ----------------
__global__ void k_deg(const int* __restrict__ dst, int* __restrict__ indeg, int E) {
  int e = blockIdx.x * 256 + threadIdx.x;
  if (e < E) atomicAdd(&indeg[dst[e]], 1);
}

__global__ void k_dis(const int* __restrict__ indeg, float* __restrict__ dis, int n) {
  int i = blockIdx.x * 256 + threadIdx.x;
  if (i < n) dis[i] = rsqrtf((float)(indeg[i] + 1));  // +1 self-loop
}

__global__ __launch_bounds__(1024) void k_scan(const int* __restrict__ v, int* __restrict__ rp, int n) {
  __shared__ int wsum[16];
  int t = threadIdx.x;
  int lane = t & 63, wv = t >> 6;
  int running = 0;
  for (int base = 0; base < n; base += 1024) {
    int val = (base + t < n) ? v[base + t] : 0;
    int s = val;
    #pragma unroll
    for (int off = 1; off < 64; off <<= 1) {
      int u = __shfl_up(s, off);
      if (lane >= off) s += u;
    }
    if (lane == 63) wsum[wv] = s;
    __syncthreads();
    int wadd = 0;
    for (int w = 0; w < wv; ++w) wadd += wsum[w];
    if (base + t < n) rp[base + t] = running + wadd + s - val;  // exclusive
    int tot = 0;
    #pragma unroll
    for (int w = 0; w < 16; ++w) tot += wsum[w];
    running += tot;
    __syncthreads();
  }
  if (t == 0) rp[n] = running;
}

__global__ void k_fill(const int* __restrict__ src, const int* __restrict__ dst,
                       const float* __restrict__ dis, int* __restrict__ cursor,
                       int* __restrict__ csrc, float* __restrict__ cw, int E) {
  int e = blockIdx.x * 256 + threadIdx.x;
  if (e >= E) return;
  int s = src[e], d = dst[e];
  int pos = atomicAdd(&cursor[d], 1);
  csrc[pos] = s;
  cw[pos] = dis[s] * dis[d];
}

// ---------------- repack: fp32 -> bf16 cast / transpose ----------------
__global__ void k_cast(const float* __restrict__ in, us16* __restrict__ out, int n) {
  int i = (blockIdx.x * 256 + threadIdx.x) * 4;
  if (i >= n) return;
  float4 v = *(const float4*)(in + i);
  *(ushort4*)(out + i) = make_ushort4(f2b(v.x), f2b(v.y), f2b(v.z), f2b(v.w));
}

// in [R,C] fp32 -> out [C,R] bf16
__global__ void k_tpose(const float* __restrict__ in, us16* __restrict__ out, int R, int C) {
  int t = blockIdx.x * 256 + threadIdx.x;
  if (t >= R * C) return;
  int r = t % R, c = t / R;
  out[(size_t)c * R + r] = f2b(in[(size_t)r * C + c]);
}

// ---------------- bf16 MFMA GEMM: C = act(A[M,K] @ Bt[Nc,K]^T + bias) ----------------
// block 128x128, 4 waves (2x2), wave tile 64x64 (4x4 frags of 16x16x32), K-step 64.
// Requires: K % 64 == 0, Nc % 128 == 0. M arbitrary (guarded).
template<int ACT, int BIAS, int WF32, int WBF16>
__global__ __launch_bounds__(256) void k_mm(const us16* __restrict__ A,
                                            const us16* __restrict__ Bt,
                                            const float* __restrict__ bias,
                                            float* __restrict__ Cf,
                                            us16* __restrict__ Cb,
                                            int M, int K, int Nc) {
  __shared__ __align__(16) us16 As[128 * 72];  // stride 72 bf16 = 144B: conflict-light
  __shared__ __align__(16) us16 Bs[128 * 72];
  const int bm = blockIdx.x * 128;
  const int bn = blockIdx.y * 128;
  const int tid = threadIdx.x;
  const int lane = tid & 63;
  const int wave = tid >> 6;
  const int wm = (wave >> 1) * 64;
  const int wn = (wave & 1) * 64;
  const int lr = lane & 15;   // frag row (A) / out-col (B, C)
  const int lk = lane >> 4;   // k-group
  const int sr = tid >> 3;    // staging row 0..31
  const int sc = (tid & 7) * 8;  // staging col chunk (8 bf16 = 16B)
  f32x4 acc[4][4] = {};
  for (int k0 = 0; k0 < K; k0 += 64) {
    #pragma unroll
    for (int it = 0; it < 4; ++it) {
      int r = sr + it * 32;
      int gr = bm + r;
      int4 va = make_int4(0, 0, 0, 0);
      if (gr < M) va = *(const int4*)(A + (size_t)gr * K + k0 + sc);
      *(int4*)(&As[r * 72 + sc]) = va;
      int4 vb = *(const int4*)(Bt + (size_t)(bn + r) * K + k0 + sc);
      *(int4*)(&Bs[r * 72 + sc]) = vb;
    }
    __syncthreads();
    #pragma unroll
    for (int kk = 0; kk < 2; ++kk) {
      bf16x8 af[4], bq[4];
      #pragma unroll
      for (int i = 0; i < 4; ++i)
        af[i] = *(const bf16x8*)(&As[(wm + i * 16 + lr) * 72 + kk * 32 + lk * 8]);
      #pragma unroll
      for (int j = 0; j < 4; ++j)
        bq[j] = *(const bf16x8*)(&Bs[(wn + j * 16 + lr) * 72 + kk * 32 + lk * 8]);
      #pragma unroll
      for (int i = 0; i < 4; ++i)
        #pragma unroll
        for (int j = 0; j < 4; ++j)
          acc[i][j] = __builtin_amdgcn_mfma_f32_16x16x32_bf16(af[i], bq[j], acc[i][j], 0, 0, 0);
    }
    __syncthreads();
  }
  float bb[4];
  #pragma unroll
  for (int j = 0; j < 4; ++j) bb[j] = BIAS ? bias[bn + wn + j * 16 + lr] : 0.0f;
  // C/D layout: col = lane&15, row = (lane>>4)*4 + q  [m89-verified]
  #pragma unroll
  for (int i = 0; i < 4; ++i) {
    #pragma unroll
    for (int q = 0; q < 4; ++q) {
      int row = bm + wm + i * 16 + lk * 4 + q;
      if (row < M) {
        #pragma unroll
        for (int j = 0; j < 4; ++j) {
          int col = bn + wn + j * 16 + lr;
          float v = acc[i][j][q] + bb[j];
          if (ACT) v = lrelu(v);
          if (WF32) Cf[(size_t)row * Nc + col] = v;
          if (WBF16) Cb[(size_t)row * Nc + col] = f2b(v);
        }
      }
    }
  }
}

// ---------------- CSR aggregation (bf16 in/out): out[n] = lrelu(sum w_e*hw[src_e] + dis^2*hw[n] + bias) ----------------
template<int F>
__global__ __launch_bounds__(256) void k_agg(const us16* __restrict__ hw, const int* __restrict__ rp,
                                             const int* __restrict__ csrc, const float* __restrict__ cw,
                                             const float* __restrict__ dis, const float* __restrict__ bias,
                                             us16* __restrict__ outp, int M) {
  int gw = (int)((blockIdx.x * 256 + threadIdx.x) >> 6);  // one wave per node
  int lane = threadIdx.x & 63;
  if (gw >= M) return;
  constexpr int V = F / 64;
  float acc[V];
  float dn = dis[gw];
  float sw = dn * dn;
  {
    const us16* p = hw + (size_t)gw * F + lane * V;
    if constexpr (V == 4) {
      ushort4 t = *(const ushort4*)p;
      acc[0] = b2f(t.x) * sw; acc[1] = b2f(t.y) * sw; acc[2] = b2f(t.z) * sw; acc[3] = b2f(t.w) * sw;
    } else {
      ushort2 t = *(const ushort2*)p;
      acc[0] = b2f(t.x) * sw; acc[1] = b2f(t.y) * sw;
    }
  }
  int e0 = rp[gw], e1 = rp[gw + 1];
  for (int e = e0; e < e1; ++e) {
    int s = csrc[e];
    float w = cw[e];
    const us16* p = hw + (size_t)s * F + lane * V;
    if constexpr (V == 4) {
      ushort4 t = *(const ushort4*)p;
      acc[0] = fmaf(w, b2f(t.x), acc[0]); acc[1] = fmaf(w, b2f(t.y), acc[1]);
      acc[2] = fmaf(w, b2f(t.z), acc[2]); acc[3] = fmaf(w, b2f(t.w), acc[3]);
    } else {
      ushort2 t = *(const ushort2*)p;
      acc[0] = fmaf(w, b2f(t.x), acc[0]); acc[1] = fmaf(w, b2f(t.y), acc[1]);
    }
  }
  if constexpr (V == 4) {
    float4 b4 = *(const float4*)(bias + lane * 4);
    *(ushort4*)(outp + (size_t)gw * F + lane * 4) =
        make_ushort4(f2b(lrelu(acc[0] + b4.x)), f2b(lrelu(acc[1] + b4.y)),
                     f2b(lrelu(acc[2] + b4.z)), f2b(lrelu(acc[3] + b4.w)));
  } else {
    float2 b2_ = *(const float2*)(bias + lane * 2);
    *(ushort2*)(outp + (size_t)gw * F + lane * 2) =
        make_ushort2(f2b(lrelu(acc[0] + b2_.x)), f2b(lrelu(acc[1] + b2_.y)));
  }
}

// ---------------- GRU gates: out = (1-z)*n + z*h ----------------
// gi/gh bf16 [M, 3H] (biases already added by GEMM), hp fp32 [M,H]
template<int H, int WB>
__global__ __launch_bounds__(256) void k_gates(const us16* __restrict__ gi, const us16* __restrict__ gh,
                                               const float* __restrict__ hp, float* __restrict__ emb,
                                               us16* __restrict__ embb, int M) {
  const int per = H / 4;
  int t = blockIdx.x * 256 + threadIdx.x;
  int m = t / per;
  int jb = (t - m * per) * 4;
  if (m >= M) return;
  const us16* gir = gi + (size_t)m * (3 * H) + jb;
  const us16* ghr = gh + (size_t)m * (3 * H) + jb;
  ushort4 vir = *(const ushort4*)(gir);
  ushort4 viz = *(const ushort4*)(gir + H);
  ushort4 vin = *(const ushort4*)(gir + 2 * H);
  ushort4 vhr = *(const ushort4*)(ghr);
  ushort4 vhz = *(const ushort4*)(ghr + H);
  ushort4 vhn = *(const ushort4*)(ghr + 2 * H);
  float4 h4 = *(const float4*)(hp + (size_t)m * H + jb);
  float ir[4] = {b2f(vir.x), b2f(vir.y), b2f(vir.z), b2f(vir.w)};
  float iz[4] = {b2f(viz.x), b2f(viz.y), b2f(viz.z), b2f(viz.w)};
  float inn[4] = {b2f(vin.x), b2f(vin.y), b2f(vin.z), b2f(vin.w)};
  float hr[4] = {b2f(vhr.x), b2f(vhr.y), b2f(vhr.z), b2f(vhr.w)};
  float hz[4] = {b2f(vhz.x), b2f(vhz.y), b2f(vhz.z), b2f(vhz.w)};
  float hn[4] = {b2f(vhn.x), b2f(vhn.y), b2f(vhn.z), b2f(vhn.w)};
  float hv[4] = {h4.x, h4.y, h4.z, h4.w};
  float o[4];
  #pragma unroll
  for (int j = 0; j < 4; ++j) {
    float r = fsigmoid(ir[j] + hr[j]);
    float z = fsigmoid(iz[j] + hz[j]);
    float n = ftanh(inn[j] + r * hn[j]);
    o[j] = (1.0f - z) * n + z * hv[j];
  }
  *(float4*)(emb + (size_t)m * H + jb) = make_float4(o[0], o[1], o[2], o[3]);
  if (WB) {
    *(ushort4*)(embb + (size_t)m * H + jb) = make_ushort4(f2b(o[0]), f2b(o[1]), f2b(o[2]), f2b(o[3]));
  }
}

// ---------------- post head: out[n] = sum_cols(emb1 @ Wpost + bpost) ----------------
__global__ __launch_bounds__(256) void k_post(const float* __restrict__ emb, const float* __restrict__ Wpost,
                                              const float* __restrict__ bpost, float* __restrict__ outv, int M) {
  int gw = (int)((blockIdx.x * 256 + threadIdx.x) >> 6);
  int lane = threadIdx.x & 63;
  if (gw >= M) return;
  float2 ev = *(const float2*)(emb + (size_t)gw * 128 + lane * 2);
  float4 wv = *(const float4*)(Wpost + lane * 4);
  float p = ev.x * (wv.x + wv.y) + ev.y * (wv.z + wv.w);
  #pragma unroll
  for (int o = 32; o > 0; o >>= 1) p += __shfl_xor(p, o);
  if (lane == 0) outv[gw] = p + bpost[0] + bpost[1];
}

extern "C" void kernel_launch(void* const* d_in, const int* in_sizes, int n_in,
                              void* d_out, int out_size, void* d_ws, size_t ws_size,
                              hipStream_t stream) {
  const float* x     = (const float*)d_in[0];
  const int*   ei    = (const int*)d_in[1];
  const float* prev0 = (const float*)d_in[2];
  const float* prev1 = (const float*)d_in[3];
  const float* Wp1   = (const float*)d_in[4];
  const float* bp1   = (const float*)d_in[5];
  const float* Wp2   = (const float*)d_in[6];
  const float* bp2   = (const float*)d_in[7];
  const float* Wc1   = (const float*)d_in[8];
  const float* bc1   = (const float*)d_in[9];
  const float* Wc2   = (const float*)d_in[10];
  const float* bc2   = (const float*)d_in[11];
  const float* Wih1  = (const float*)d_in[12];
  const float* Whh1  = (const float*)d_in[13];
  const float* bih1  = (const float*)d_in[14];
  const float* bhh1  = (const float*)d_in[15];
  const float* Wih2  = (const float*)d_in[16];
  const float* Whh2  = (const float*)d_in[17];
  const float* bih2  = (const float*)d_in[18];
  const float* bhh2  = (const float*)d_in[19];
  const float* Wpost = (const float*)d_in[20];
  const float* bpost = (const float*)d_in[21];

  const int N = in_sizes[0] / 128;   // 100000
  const int E = in_sizes[1] / 2;     // 1600000
  const int* srcp = ei;
  const int* dstp = ei + E;

  char* wsb = (char*)d_ws;
  size_t off = 0;
  auto alloc = [&](size_t bytes) -> void* {
    void* p = wsb + off;
    off = (off + bytes + 255) & ~(size_t)255;
    return p;
  };
  const int CH = 25000;  // M-chunk for GRU gi/gh scratch
  float* dis    = (float*)alloc((size_t)N * 4);
  int*   indeg  = (int*)alloc((size_t)N * 4);
  int*   rp     = (int*)alloc((size_t)(N + 1) * 4);
  int*   cursor = (int*)alloc((size_t)N * 4);
  int*   csrc   = (int*)alloc((size_t)E * 4);
  float* cw     = (float*)alloc((size_t)E * 4);
  us16* xb    = (us16*)alloc((size_t)N * 128 * 2);
  us16* p0b   = (us16*)alloc((size_t)N * 256 * 2);
  us16* p1b   = (us16*)alloc((size_t)N * 128 * 2);
  us16* WtP1  = (us16*)alloc((size_t)256 * 128 * 2);
  us16* WtP2  = (us16*)alloc((size_t)128 * 256 * 2);
  us16* WtC1  = (us16*)alloc((size_t)256 * 128 * 2);
  us16* WtC2  = (us16*)alloc((size_t)128 * 256 * 2);
  us16* Wih1b = (us16*)alloc((size_t)768 * 256 * 2);
  us16* Whh1b = (us16*)alloc((size_t)768 * 256 * 2);
  us16* Wih2b = (us16*)alloc((size_t)384 * 128 * 2);
  us16* Whh2b = (us16*)alloc((size_t)384 * 128 * 2);
  us16* bufA  = (us16*)alloc((size_t)N * 256 * 2);
  us16* bufB  = (us16*)alloc((size_t)N * 128 * 2);
  us16* bufC  = (us16*)alloc((size_t)N * 256 * 2);
  us16* emb0b = (us16*)alloc((size_t)N * 256 * 2);
  us16* gi_ch = (us16*)alloc((size_t)CH * 768 * 2);
  us16* gh_ch = (us16*)alloc((size_t)CH * 768 * 2);
  (void)ws_size; (void)n_in; (void)out_size;

  float* outv = (float*)d_out;
  float* emb0 = outv + N;
  float* emb1 = emb0 + (size_t)N * 256;

  auto cg = [](long n) { return (unsigned)((n / 4 + 255) / 256); };

  // weight/activation repack
  k_cast<<<cg((long)N * 128), 256, 0, stream>>>(x, xb, N * 128);
  k_cast<<<cg((long)N * 256), 256, 0, stream>>>(prev0, p0b, N * 256);
  k_cast<<<cg((long)N * 128), 256, 0, stream>>>(prev1, p1b, N * 128);
  k_cast<<<cg(768 * 256), 256, 0, stream>>>(Wih1, Wih1b, 768 * 256);
  k_cast<<<cg(768 * 256), 256, 0, stream>>>(Whh1, Whh1b, 768 * 256);
  k_cast<<<cg(384 * 128), 256, 0, stream>>>(Wih2, Wih2b, 384 * 128);
  k_cast<<<cg(384 * 128), 256, 0, stream>>>(Whh2, Whh2b, 384 * 128);
  k_tpose<<<(128 * 256 + 255) / 256, 256, 0, stream>>>(Wp1, WtP1, 128, 256);
  k_tpose<<<(256 * 128 + 255) / 256, 256, 0, stream>>>(Wp2, WtP2, 256, 128);
  k_tpose<<<(128 * 256 + 255) / 256, 256, 0, stream>>>(Wc1, WtC1, 128, 256);
  k_tpose<<<(256 * 128 + 255) / 256, 256, 0, stream>>>(Wc2, WtC2, 256, 128);

  // CSR build
  hipMemsetAsync(indeg, 0, (size_t)N * 4, stream);
  k_deg<<<(E + 255) / 256, 256, 0, stream>>>(dstp, indeg, E);
  k_dis<<<(N + 255) / 256, 256, 0, stream>>>(indeg, dis, N);
  k_scan<<<1, 1024, 0, stream>>>(indeg, rp, N);
  hipMemcpyAsync(cursor, rp, (size_t)N * 4, hipMemcpyDeviceToDevice, stream);
  k_fill<<<(E + 255) / 256, 256, 0, stream>>>(srcp, dstp, dis, cursor, csrc, cw, E);

  const int MB = (N + 127) / 128;  // 782
  // preprocess MLP
  k_mm<1, 1, 0, 1><<<dim3(MB, 2), 256, 0, stream>>>(xb, WtP1, bp1, nullptr, bufA, N, 128, 256);
  k_mm<1, 1, 0, 1><<<dim3(MB, 1), 256, 0, stream>>>(bufA, WtP2, bp2, nullptr, bufB, N, 256, 128);
  // GCN1 linear + aggregate
  k_mm<0, 0, 0, 1><<<dim3(MB, 2), 256, 0, stream>>>(bufB, WtC1, nullptr, nullptr, bufA, N, 128, 256);
  k_agg<256><<<(N + 3) / 4, 256, 0, stream>>>(bufA, rp, csrc, cw, dis, bc1, bufC, N);
  // GRU1 (chunked): gi = x@Wih^T+bih, gh = h@Whh^T+bhh, gates
  const int CB = (CH + 127) / 128;  // 196
  for (int c = 0; c < 4; ++c) {
    size_t m0 = (size_t)c * CH;
    k_mm<0, 1, 0, 1><<<dim3(CB, 6), 256, 0, stream>>>(bufC + m0 * 256, Wih1b, bih1, nullptr, gi_ch, CH, 256, 768);
    k_mm<0, 1, 0, 1><<<dim3(CB, 6), 256, 0, stream>>>(p0b + m0 * 256, Whh1b, bhh1, nullptr, gh_ch, CH, 256, 768);
    k_gates<256, 1><<<(CH * 64 + 255) / 256, 256, 0, stream>>>(gi_ch, gh_ch, prev0 + m0 * 256,
                                                               emb0 + m0 * 256, emb0b + m0 * 256, CH);
  }
  // GCN2 linear + aggregate
  k_mm<0, 0, 0, 1><<<dim3(MB, 1), 256, 0, stream>>>(emb0b, WtC2, nullptr, nullptr, bufB, N, 256, 128);
  k_agg<128><<<(N + 3) / 4, 256, 0, stream>>>(bufB, rp, csrc, cw, dis, bc2, bufC, N);
  // GRU2 (chunked)
  for (int c = 0; c < 4; ++c) {
    size_t m0 = (size_t)c * CH;
    k_mm<0, 1, 0, 1><<<dim3(CB, 3), 256, 0, stream>>>(bufC + m0 * 128, Wih2b, bih2, nullptr, gi_ch, CH, 128, 384);
    k_mm<0, 1, 0, 1><<<dim3(CB, 3), 256, 0, stream>>>(p1b + m0 * 128, Whh2b, bhh2, nullptr, gh_ch, CH, 128, 384);
    k_gates<128, 0><<<(CH * 32 + 255) / 256, 256, 0, stream>>>(gi_ch, gh_ch, prev1 + m0 * 128,
                                                               emb1 + m0 * 128, nullptr, CH);
  }
  // post head
  k_post<<<(N + 3) / 4, 256, 0, stream>>>(emb1, Wpost, bpost, outv, N);
}

// Round 3
// 988.235 us; speedup vs baseline: 2.5917x; 1.3194x over previous
//
#include <hip/hip_runtime.h>
#include <cstdint>
#include <cstddef>

typedef __bf16 bf16x8 __attribute__((ext_vector_type(8)));
typedef float f32x4 __attribute__((ext_vector_type(4)));
typedef unsigned short us16;

__device__ __forceinline__ float lrelu(float v) { return v >= 0.0f ? v : 0.01f * v; }
__device__ __forceinline__ float fsigmoid(float x) {
  x = fminf(fmaxf(x, -30.0f), 30.0f);
  return 1.0f / (1.0f + __expf(-x));
}
__device__ __forceinline__ float ftanh(float x) {
  x = fminf(fmaxf(x, -15.0f), 15.0f);
  float e = __expf(2.0f * x);
  return (e - 1.0f) / (e + 1.0f);
}
__device__ __forceinline__ us16 f2b(float f) {
  unsigned int u = __builtin_bit_cast(unsigned int, f);
  u = (u + 0x7fffu + ((u >> 16) & 1u)) >> 16;
  return (us16)u;
}
__device__ __forceinline__ float b2f(us16 h) {
  unsigned int u = ((unsigned int)h) << 16;
  return __builtin_bit_cast(float, u);
}
__device__ __forceinline__ void unp8(int4 v, float* t) {
  unsigned a = (unsigned)v.x, b = (unsigned)v.y, c = (unsigned)v.z, d = (unsigned)v.w;
  t[0] = b2f((us16)(a & 0xffff)); t[1] = b2f((us16)(a >> 16));
  t[2] = b2f((us16)(b & 0xffff)); t[3] = b2f((us16)(b >> 16));
  t[4] = b2f((us16)(c & 0xffff)); t[5] = b2f((us16)(c >> 16));
  t[6] = b2f((us16)(d & 0xffff)); t[7] = b2f((us16)(d >> 16));
}

// ---------------- degree / norm / CSR build ----------------
__global__ void k_deg(const int* __restrict__ dst, int* __restrict__ indeg, int E) {
  int e = blockIdx.x * 256 + threadIdx.x;
  if (e < E) atomicAdd(&indeg[dst[e]], 1);
}

__global__ void k_dis(const int* __restrict__ indeg, float* __restrict__ dis, int n) {
  int i = blockIdx.x * 256 + threadIdx.x;
  if (i < n) dis[i] = rsqrtf((float)(indeg[i] + 1));  // +1 self-loop
}

__global__ __launch_bounds__(1024) void k_scan(const int* __restrict__ v, int* __restrict__ rp, int n) {
  __shared__ int wsum[16];
  int t = threadIdx.x;
  int lane = t & 63, wv = t >> 6;
  int running = 0;
  for (int base = 0; base < n; base += 1024) {
    int val = (base + t < n) ? v[base + t] : 0;
    int s = val;
    #pragma unroll
    for (int off = 1; off < 64; off <<= 1) {
      int u = __shfl_up(s, off);
      if (lane >= off) s += u;
    }
    if (lane == 63) wsum[wv] = s;
    __syncthreads();
    int wadd = 0;
    for (int w = 0; w < wv; ++w) wadd += wsum[w];
    if (base + t < n) rp[base + t] = running + wadd + s - val;  // exclusive
    int tot = 0;
    #pragma unroll
    for (int w = 0; w < 16; ++w) tot += wsum[w];
    running += tot;
    __syncthreads();
  }
  if (t == 0) rp[n] = running;
}

__global__ void k_fill(const int* __restrict__ src, const int* __restrict__ dst,
                       const float* __restrict__ dis, int* __restrict__ cursor,
                       int* __restrict__ csrc, float* __restrict__ cw, int E) {
  int e = blockIdx.x * 256 + threadIdx.x;
  if (e >= E) return;
  int s = src[e], d = dst[e];
  int pos = atomicAdd(&cursor[d], 1);
  csrc[pos] = s;
  cw[pos] = dis[s] * dis[d];
}

// ---------------- repack: fp32 -> bf16 cast / transpose ----------------
__global__ void k_cast(const float* __restrict__ in, us16* __restrict__ out, int n) {
  int i = (blockIdx.x * 256 + threadIdx.x) * 4;
  if (i >= n) return;
  float4 v = *(const float4*)(in + i);
  *(ushort4*)(out + i) = make_ushort4(f2b(v.x), f2b(v.y), f2b(v.z), f2b(v.w));
}

// in [R,C] fp32 -> out [C,R] bf16
__global__ void k_tpose(const float* __restrict__ in, us16* __restrict__ out, int R, int C) {
  int t = blockIdx.x * 256 + threadIdx.x;
  if (t >= R * C) return;
  int r = t % R, c = t / R;
  out[(size_t)c * R + r] = f2b(in[(size_t)r * C + c]);
}

// ---------------- bf16 MFMA GEMM: C = act(A[M,K] @ Bt[Nc,K]^T + bias) ----------------
// block 128x128, 4 waves (2x2), wave tile 64x64 (4x4 frags of 16x16x32), K-step 64.
template<int ACT, int BIAS>
__global__ __launch_bounds__(256) void k_mm(const us16* __restrict__ A,
                                            const us16* __restrict__ Bt,
                                            const float* __restrict__ bias,
                                            us16* __restrict__ Cb,
                                            int M, int K, int Nc) {
  __shared__ __align__(16) us16 As[128 * 72];
  __shared__ __align__(16) us16 Bs[128 * 72];
  const int bm = blockIdx.x * 128;
  const int bn = blockIdx.y * 128;
  const int tid = threadIdx.x;
  const int lane = tid & 63;
  const int wave = tid >> 6;
  const int wm = (wave >> 1) * 64;
  const int wn = (wave & 1) * 64;
  const int lr = lane & 15;
  const int lk = lane >> 4;
  const int sr = tid >> 3;
  const int sc = (tid & 7) * 8;
  f32x4 acc[4][4] = {};
  for (int k0 = 0; k0 < K; k0 += 64) {
    #pragma unroll
    for (int it = 0; it < 4; ++it) {
      int r = sr + it * 32;
      int gr = bm + r;
      int4 va = make_int4(0, 0, 0, 0);
      if (gr < M) va = *(const int4*)(A + (size_t)gr * K + k0 + sc);
      *(int4*)(&As[r * 72 + sc]) = va;
      int4 vb = *(const int4*)(Bt + (size_t)(bn + r) * K + k0 + sc);
      *(int4*)(&Bs[r * 72 + sc]) = vb;
    }
    __syncthreads();
    #pragma unroll
    for (int kk = 0; kk < 2; ++kk) {
      bf16x8 af[4], bq[4];
      #pragma unroll
      for (int i = 0; i < 4; ++i)
        af[i] = *(const bf16x8*)(&As[(wm + i * 16 + lr) * 72 + kk * 32 + lk * 8]);
      #pragma unroll
      for (int j = 0; j < 4; ++j)
        bq[j] = *(const bf16x8*)(&Bs[(wn + j * 16 + lr) * 72 + kk * 32 + lk * 8]);
      #pragma unroll
      for (int i = 0; i < 4; ++i)
        #pragma unroll
        for (int j = 0; j < 4; ++j)
          acc[i][j] = __builtin_amdgcn_mfma_f32_16x16x32_bf16(af[i], bq[j], acc[i][j], 0, 0, 0);
    }
    __syncthreads();
  }
  float bb[4];
  #pragma unroll
  for (int j = 0; j < 4; ++j) bb[j] = BIAS ? bias[bn + wn + j * 16 + lr] : 0.0f;
  #pragma unroll
  for (int i = 0; i < 4; ++i) {
    #pragma unroll
    for (int q = 0; q < 4; ++q) {
      int row = bm + wm + i * 16 + lk * 4 + q;
      if (row < M) {
        #pragma unroll
        for (int j = 0; j < 4; ++j) {
          int col = bn + wn + j * 16 + lr;
          float v = acc[i][j][q] + bb[j];
          if (ACT) v = lrelu(v);
          Cb[(size_t)row * Nc + col] = f2b(v);
        }
      }
    }
  }
}

// ---------------- CSR aggregation, F=128: 16 lanes/node, 4 nodes/wave, edge-unrolled x2 ----------------
// out[n] = [lrelu](sum_{e:dst=n} w_e*hw[src_e] + dis[n]^2*hw[n] [+ bias])
template<int ACT>
__global__ __launch_bounds__(256) void k_agg128(const us16* __restrict__ hw, const int* __restrict__ rp,
                                                const int* __restrict__ csrc, const float* __restrict__ cw,
                                                const float* __restrict__ dis, const float* __restrict__ bias,
                                                us16* __restrict__ outp, int M) {
  int node = blockIdx.x * 16 + (threadIdx.x >> 4);
  int l = threadIdx.x & 15;
  if (node >= M) return;
  const us16* base = hw + l * 8;
  float acc[8], t0[8], t1[8];
  float dn = dis[node];
  float sw = dn * dn;
  {
    int4 v = *(const int4*)(base + (size_t)node * 128);
    unp8(v, t0);
    #pragma unroll
    for (int j = 0; j < 8; ++j) acc[j] = t0[j] * sw;
  }
  int e = rp[node], e1 = rp[node + 1];
  for (; e + 2 <= e1; e += 2) {
    int s0 = csrc[e], s1 = csrc[e + 1];
    float w0 = cw[e], w1 = cw[e + 1];
    int4 v0 = *(const int4*)(base + (size_t)s0 * 128);
    int4 v1 = *(const int4*)(base + (size_t)s1 * 128);
    unp8(v0, t0);
    unp8(v1, t1);
    #pragma unroll
    for (int j = 0; j < 8; ++j) acc[j] = fmaf(w0, t0[j], acc[j]);
    #pragma unroll
    for (int j = 0; j < 8; ++j) acc[j] = fmaf(w1, t1[j], acc[j]);
  }
  if (e < e1) {
    int s0 = csrc[e];
    float w0 = cw[e];
    int4 v0 = *(const int4*)(base + (size_t)s0 * 128);
    unp8(v0, t0);
    #pragma unroll
    for (int j = 0; j < 8; ++j) acc[j] = fmaf(w0, t0[j], acc[j]);
  }
  if (ACT) {
    float4 b0 = *(const float4*)(bias + l * 8);
    float4 b1 = *(const float4*)(bias + l * 8 + 4);
    float bb[8] = {b0.x, b0.y, b0.z, b0.w, b1.x, b1.y, b1.z, b1.w};
    #pragma unroll
    for (int j = 0; j < 8; ++j) acc[j] = lrelu(acc[j] + bb[j]);
  }
  int4 o;
  o.x = (int)((unsigned)f2b(acc[0]) | ((unsigned)f2b(acc[1]) << 16));
  o.y = (int)((unsigned)f2b(acc[2]) | ((unsigned)f2b(acc[3]) << 16));
  o.z = (int)((unsigned)f2b(acc[4]) | ((unsigned)f2b(acc[5]) << 16));
  o.w = (int)((unsigned)f2b(acc[6]) | ((unsigned)f2b(acc[7]) << 16));
  *(int4*)(outp + (size_t)node * 128 + l * 8) = o;
}

// ---------------- fused GRU cell (MFMA): emb = GRUCell(x, hprev) ----------------
// BM=64 rows, BN=64 h-cols, K=H, Kstep=32. 4 waves (2x2), wave tile 32x32.
// 6 simultaneous accumulations: gi_r,gi_z,gi_n (A=x), gh_r,gh_z,gh_n (A=hprev).
template<int H, int WB>
__global__ __launch_bounds__(256) void k_fgru(const us16* __restrict__ xb, const us16* __restrict__ hb,
                                              const float* __restrict__ hp,
                                              const us16* __restrict__ Wih, const us16* __restrict__ Whh,
                                              const float* __restrict__ bih, const float* __restrict__ bhh,
                                              float* __restrict__ emb, us16* __restrict__ embb, int M) {
  constexpr int LDW = 40;  // padded row stride (bf16): 80B -> ~2-way banks, free
  __shared__ __align__(16) us16 xs[64 * LDW];
  __shared__ __align__(16) us16 hs[64 * LDW];
  __shared__ __align__(16) us16 ws[6][64 * LDW];
  const int bm = blockIdx.x * 64;
  const int bn = blockIdx.y * 64;
  const int tid = threadIdx.x;
  const int lane = tid & 63, wave = tid >> 6;
  const int wm = (wave >> 1) * 32, wn = (wave & 1) * 32;
  const int lr = lane & 15, lk = lane >> 4;
  const int srow = tid >> 2;       // 0..63
  const int scol = (tid & 3) * 8;  // 0,8,16,24
  f32x4 acc[6][2][2] = {};
  const bool rv = (bm + srow) < M;
  const us16* xrp = xb + (size_t)(bm + srow) * H;
  const us16* hrp = hb + (size_t)(bm + srow) * H;

  for (int k0 = 0; k0 < H; k0 += 32) {
    int4 vx = rv ? *(const int4*)(xrp + k0 + scol) : make_int4(0, 0, 0, 0);
    int4 vh = rv ? *(const int4*)(hrp + k0 + scol) : make_int4(0, 0, 0, 0);
    *(int4*)(xs + srow * LDW + scol) = vx;
    *(int4*)(hs + srow * LDW + scol) = vh;
    #pragma unroll
    for (int g = 0; g < 3; ++g) {
      int4 wi = *(const int4*)(Wih + (size_t)(g * H + bn + srow) * H + k0 + scol);
      *(int4*)(ws[g] + srow * LDW + scol) = wi;
      int4 wh = *(const int4*)(Whh + (size_t)(g * H + bn + srow) * H + k0 + scol);
      *(int4*)(ws[3 + g] + srow * LDW + scol) = wh;
    }
    __syncthreads();
    bf16x8 ax[2], ah[2];
    #pragma unroll
    for (int i = 0; i < 2; ++i) {
      ax[i] = *(const bf16x8*)(xs + (wm + i * 16 + lr) * LDW + lk * 8);
      ah[i] = *(const bf16x8*)(hs + (wm + i * 16 + lr) * LDW + lk * 8);
    }
    #pragma unroll
    for (int g = 0; g < 6; ++g) {
      bf16x8 bq[2];
      #pragma unroll
      for (int j = 0; j < 2; ++j)
        bq[j] = *(const bf16x8*)(ws[g] + (wn + j * 16 + lr) * LDW + lk * 8);
      #pragma unroll
      for (int i = 0; i < 2; ++i)
        #pragma unroll
        for (int j = 0; j < 2; ++j)
          acc[g][i][j] = __builtin_amdgcn_mfma_f32_16x16x32_bf16(
              (g < 3 ? ax[i] : ah[i]), bq[j], acc[g][i][j], 0, 0, 0);
    }
    __syncthreads();
  }
  // epilogue: gates
  #pragma unroll
  for (int j = 0; j < 2; ++j) {
    int col = bn + wn + j * 16 + lr;
    float bir = bih[col], biz = bih[H + col], bin = bih[2 * H + col];
    float bhr = bhh[col], bhz = bhh[H + col], bhn = bhh[2 * H + col];
    #pragma unroll
    for (int i = 0; i < 2; ++i) {
      #pragma unroll
      for (int q = 0; q < 4; ++q) {
        int row = bm + wm + i * 16 + lk * 4 + q;
        if (row >= M) continue;
        float r = fsigmoid(acc[0][i][j][q] + bir + acc[3][i][j][q] + bhr);
        float z = fsigmoid(acc[1][i][j][q] + biz + acc[4][i][j][q] + bhz);
        float n = ftanh(acc[2][i][j][q] + bin + r * (acc[5][i][j][q] + bhn));
        float hv = hp[(size_t)row * H + col];
        float o = (1.0f - z) * n + z * hv;
        emb[(size_t)row * H + col] = o;
        if (WB) embb[(size_t)row * H + col] = f2b(o);
      }
    }
  }
}

// ---------------- post head: out[n] = sum_cols(emb1 @ Wpost + bpost) ----------------
__global__ __launch_bounds__(256) void k_post(const float* __restrict__ emb, const float* __restrict__ Wpost,
                                              const float* __restrict__ bpost, float* __restrict__ outv, int M) {
  int gw = (int)((blockIdx.x * 256 + threadIdx.x) >> 6);
  int lane = threadIdx.x & 63;
  if (gw >= M) return;
  float2 ev = *(const float2*)(emb + (size_t)gw * 128 + lane * 2);
  float4 wv = *(const float4*)(Wpost + lane * 4);
  float p = ev.x * (wv.x + wv.y) + ev.y * (wv.z + wv.w);
  #pragma unroll
  for (int o = 32; o > 0; o >>= 1) p += __shfl_xor(p, o);
  if (lane == 0) outv[gw] = p + bpost[0] + bpost[1];
}

extern "C" void kernel_launch(void* const* d_in, const int* in_sizes, int n_in,
                              void* d_out, int out_size, void* d_ws, size_t ws_size,
                              hipStream_t stream) {
  const float* x     = (const float*)d_in[0];
  const int*   ei    = (const int*)d_in[1];
  const float* prev0 = (const float*)d_in[2];
  const float* prev1 = (const float*)d_in[3];
  const float* Wp1   = (const float*)d_in[4];
  const float* bp1   = (const float*)d_in[5];
  const float* Wp2   = (const float*)d_in[6];
  const float* bp2   = (const float*)d_in[7];
  const float* Wc1   = (const float*)d_in[8];
  const float* bc1   = (const float*)d_in[9];
  const float* Wc2   = (const float*)d_in[10];
  const float* bc2   = (const float*)d_in[11];
  const float* Wih1  = (const float*)d_in[12];
  const float* Whh1  = (const float*)d_in[13];
  const float* bih1  = (const float*)d_in[14];
  const float* bhh1  = (const float*)d_in[15];
  const float* Wih2  = (const float*)d_in[16];
  const float* Whh2  = (const float*)d_in[17];
  const float* bih2  = (const float*)d_in[18];
  const float* bhh2  = (const float*)d_in[19];
  const float* Wpost = (const float*)d_in[20];
  const float* bpost = (const float*)d_in[21];

  const int N = in_sizes[0] / 128;   // 100000
  const int E = in_sizes[1] / 2;     // 1600000
  const int* srcp = ei;
  const int* dstp = ei + E;

  char* wsb = (char*)d_ws;
  size_t off = 0;
  auto alloc = [&](size_t bytes) -> void* {
    void* p = wsb + off;
    off = (off + bytes + 255) & ~(size_t)255;
    return p;
  };
  float* dis    = (float*)alloc((size_t)N * 4);
  int*   indeg  = (int*)alloc((size_t)N * 4);
  int*   rp     = (int*)alloc((size_t)(N + 1) * 4);
  int*   cursor = (int*)alloc((size_t)N * 4);
  int*   csrc   = (int*)alloc((size_t)E * 4);
  float* cw     = (float*)alloc((size_t)E * 4);
  us16* xb    = (us16*)alloc((size_t)N * 128 * 2);
  us16* p0b   = (us16*)alloc((size_t)N * 256 * 2);
  us16* p1b   = (us16*)alloc((size_t)N * 128 * 2);
  us16* WtP1  = (us16*)alloc((size_t)256 * 128 * 2);
  us16* WtP2  = (us16*)alloc((size_t)128 * 256 * 2);
  us16* WtC1  = (us16*)alloc((size_t)256 * 128 * 2);
  us16* WtC2  = (us16*)alloc((size_t)128 * 256 * 2);
  us16* Wih1b = (us16*)alloc((size_t)768 * 256 * 2);
  us16* Whh1b = (us16*)alloc((size_t)768 * 256 * 2);
  us16* Wih2b = (us16*)alloc((size_t)384 * 128 * 2);
  us16* Whh2b = (us16*)alloc((size_t)384 * 128 * 2);
  us16* bufA  = (us16*)alloc((size_t)N * 256 * 2);  // MLP hidden / GCN1 out
  us16* bufB  = (us16*)alloc((size_t)N * 128 * 2);  // MLP out / GCN2 lin out
  us16* bufD  = (us16*)alloc((size_t)N * 128 * 2);  // agg out
  us16* emb0b = (us16*)alloc((size_t)N * 256 * 2);
  (void)ws_size; (void)n_in; (void)out_size;

  float* outv = (float*)d_out;
  float* emb0 = outv + N;
  float* emb1 = emb0 + (size_t)N * 256;

  auto cg = [](long n) { return (unsigned)((n / 4 + 255) / 256); };

  // weight/activation repack
  k_cast<<<cg((long)N * 128), 256, 0, stream>>>(x, xb, N * 128);
  k_cast<<<cg((long)N * 256), 256, 0, stream>>>(prev0, p0b, N * 256);
  k_cast<<<cg((long)N * 128), 256, 0, stream>>>(prev1, p1b, N * 128);
  k_cast<<<cg(768 * 256), 256, 0, stream>>>(Wih1, Wih1b, 768 * 256);
  k_cast<<<cg(768 * 256), 256, 0, stream>>>(Whh1, Whh1b, 768 * 256);
  k_cast<<<cg(384 * 128), 256, 0, stream>>>(Wih2, Wih2b, 384 * 128);
  k_cast<<<cg(384 * 128), 256, 0, stream>>>(Whh2, Whh2b, 384 * 128);
  k_tpose<<<(128 * 256 + 255) / 256, 256, 0, stream>>>(Wp1, WtP1, 128, 256);
  k_tpose<<<(256 * 128 + 255) / 256, 256, 0, stream>>>(Wp2, WtP2, 256, 128);
  k_tpose<<<(128 * 256 + 255) / 256, 256, 0, stream>>>(Wc1, WtC1, 128, 256);
  k_tpose<<<(256 * 128 + 255) / 256, 256, 0, stream>>>(Wc2, WtC2, 256, 128);

  // CSR build
  hipMemsetAsync(indeg, 0, (size_t)N * 4, stream);
  k_deg<<<(E + 255) / 256, 256, 0, stream>>>(dstp, indeg, E);
  k_dis<<<(N + 255) / 256, 256, 0, stream>>>(indeg, dis, N);
  k_scan<<<1, 1024, 0, stream>>>(indeg, rp, N);
  hipMemcpyAsync(cursor, rp, (size_t)N * 4, hipMemcpyDeviceToDevice, stream);
  k_fill<<<(E + 255) / 256, 256, 0, stream>>>(srcp, dstp, dis, cursor, csrc, cw, E);

  const int MB = (N + 127) / 128;   // 782 (k_mm)
  const int FB = (N + 63) / 64;     // 1563 (k_fgru)
  const int AB = (N + 15) / 16;     // 6250 (k_agg128)

  // preprocess MLP
  k_mm<1, 1><<<dim3(MB, 2), 256, 0, stream>>>(xb, WtP1, bp1, bufA, N, 128, 256);
  k_mm<1, 1><<<dim3(MB, 1), 256, 0, stream>>>(bufA, WtP2, bp2, bufB, N, 256, 128);
  // GCN1: aggregate FIRST (linearity: agg(h@W) == agg(h)@W), then linear+bias+leaky
  k_agg128<0><<<AB, 256, 0, stream>>>(bufB, rp, csrc, cw, dis, nullptr, bufD, N);
  k_mm<1, 1><<<dim3(MB, 2), 256, 0, stream>>>(bufD, WtC1, bc1, bufA, N, 128, 256);
  // GRU1 fused
  k_fgru<256, 1><<<dim3(FB, 4), 256, 0, stream>>>(bufA, p0b, prev0, Wih1b, Whh1b, bih1, bhh1,
                                                  emb0, emb0b, N);
  // GCN2: linear first (256->128), then aggregate with bias+leaky
  k_mm<0, 0><<<dim3(MB, 1), 256, 0, stream>>>(emb0b, WtC2, nullptr, bufB, N, 256, 128);
  k_agg128<1><<<AB, 256, 0, stream>>>(bufB, rp, csrc, cw, dis, bc2, bufD, N);
  // GRU2 fused
  k_fgru<128, 0><<<dim3(FB, 2), 256, 0, stream>>>(bufD, p1b, prev1, Wih2b, Whh2b, bih2, bhh2,
                                                  emb1, nullptr, N);
  // post head
  k_post<<<(N + 3) / 4, 256, 0, stream>>>(emb1, Wpost, bpost, outv, N);
}

// Round 4
// 818.565 us; speedup vs baseline: 3.1290x; 1.2073x over previous
//
#include <hip/hip_runtime.h>
#include <cstdint>
#include <cstddef>

typedef __bf16 bf16x8 __attribute__((ext_vector_type(8)));
typedef float f32x4 __attribute__((ext_vector_type(4)));
typedef unsigned short us16;

__device__ __forceinline__ float lrelu(float v) { return v >= 0.0f ? v : 0.01f * v; }
__device__ __forceinline__ float fsigmoid(float x) {
  x = fminf(fmaxf(x, -30.0f), 30.0f);
  return 1.0f / (1.0f + __expf(-x));
}
__device__ __forceinline__ float ftanh(float x) {
  x = fminf(fmaxf(x, -15.0f), 15.0f);
  float e = __expf(2.0f * x);
  return (e - 1.0f) / (e + 1.0f);
}
__device__ __forceinline__ us16 f2b(float f) {
  unsigned int u = __builtin_bit_cast(unsigned int, f);
  u = (u + 0x7fffu + ((u >> 16) & 1u)) >> 16;
  return (us16)u;
}
__device__ __forceinline__ float b2f(us16 h) {
  unsigned int u = ((unsigned int)h) << 16;
  return __builtin_bit_cast(float, u);
}
__device__ __forceinline__ void unp8(int4 v, float* t) {
  unsigned a = (unsigned)v.x, b = (unsigned)v.y, c = (unsigned)v.z, d = (unsigned)v.w;
  t[0] = b2f((us16)(a & 0xffff)); t[1] = b2f((us16)(a >> 16));
  t[2] = b2f((us16)(b & 0xffff)); t[3] = b2f((us16)(b >> 16));
  t[4] = b2f((us16)(c & 0xffff)); t[5] = b2f((us16)(c >> 16));
  t[6] = b2f((us16)(d & 0xffff)); t[7] = b2f((us16)(d >> 16));
}

// ---------------- degree / norm / CSR build ----------------
__global__ void k_deg(const int* __restrict__ dst, int* __restrict__ indeg, int E) {
  int e = blockIdx.x * 256 + threadIdx.x;
  if (e < E) atomicAdd(&indeg[dst[e]], 1);
}

__global__ void k_dis(const int* __restrict__ indeg, float* __restrict__ dis, int n) {
  int i = blockIdx.x * 256 + threadIdx.x;
  if (i < n) dis[i] = rsqrtf((float)(indeg[i] + 1));  // +1 self-loop
}

// 3-phase parallel exclusive scan of indeg -> rp
__global__ __launch_bounds__(1024) void k_scan1(const int* __restrict__ v, int* __restrict__ rp,
                                                int* __restrict__ part, int n) {
  __shared__ int wsum[16];
  int base = blockIdx.x << 10;
  int t = threadIdx.x, lane = t & 63, wv = t >> 6;
  int val = (base + t < n) ? v[base + t] : 0;
  int s = val;
  #pragma unroll
  for (int off = 1; off < 64; off <<= 1) {
    int u = __shfl_up(s, off);
    if (lane >= off) s += u;
  }
  if (lane == 63) wsum[wv] = s;
  __syncthreads();
  int wadd = 0;
  #pragma unroll
  for (int w = 0; w < 16; ++w) wadd += (w < wv) ? wsum[w] : 0;
  if (base + t < n) rp[base + t] = wadd + s - val;  // exclusive within chunk
  if (t == 0) {
    int tot = 0;
    #pragma unroll
    for (int w = 0; w < 16; ++w) tot += wsum[w];
    part[blockIdx.x] = tot;
  }
}

__global__ __launch_bounds__(1024) void k_scan2(int* __restrict__ p, int nc) {
  __shared__ int wsum[16];
  int t = threadIdx.x, lane = t & 63, wv = t >> 6;
  int val = (t < nc) ? p[t] : 0;
  int s = val;
  #pragma unroll
  for (int off = 1; off < 64; off <<= 1) {
    int u = __shfl_up(s, off);
    if (lane >= off) s += u;
  }
  if (lane == 63) wsum[wv] = s;
  __syncthreads();
  int wadd = 0;
  #pragma unroll
  for (int w = 0; w < 16; ++w) wadd += (w < wv) ? wsum[w] : 0;
  if (t < nc) p[t] = wadd + s - val;  // exclusive
}

__global__ void k_scan3(int* __restrict__ rp, const int* __restrict__ part, int n, int total) {
  int i = blockIdx.x * 256 + threadIdx.x;
  if (i < n) rp[i] += part[i >> 10];
  else if (i == n) rp[n] = total;
}

__global__ void k_fill(const int* __restrict__ src, const int* __restrict__ dst,
                       const float* __restrict__ dis, int* __restrict__ cursor,
                       int* __restrict__ csrc, float* __restrict__ cw, int E) {
  int e = blockIdx.x * 256 + threadIdx.x;
  if (e >= E) return;
  int s = src[e], d = dst[e];
  int pos = atomicAdd(&cursor[d], 1);
  csrc[pos] = s;
  cw[pos] = dis[s] * dis[d];
}

// ---------------- repack: fp32 -> bf16 cast / transpose ----------------
__global__ void k_cast(const float* __restrict__ in, us16* __restrict__ out, int n) {
  int i = (blockIdx.x * 256 + threadIdx.x) * 4;
  if (i >= n) return;
  float4 v = *(const float4*)(in + i);
  *(ushort4*)(out + i) = make_ushort4(f2b(v.x), f2b(v.y), f2b(v.z), f2b(v.w));
}

// in [R,C] fp32 -> out [C,R] bf16
__global__ void k_tpose(const float* __restrict__ in, us16* __restrict__ out, int R, int C) {
  int t = blockIdx.x * 256 + threadIdx.x;
  if (t >= R * C) return;
  int r = t % R, c = t / R;
  out[(size_t)c * R + r] = f2b(in[(size_t)r * C + c]);
}

// ---------------- bf16 MFMA GEMM: C = act(A[M,K] @ Bt[Nc,K]^T + bias) ----------------
// block 128x128, 4 waves (2x2), wave tile 64x64, K-step 64. 1-D grid, bn-inner swizzle.
template<int ACT, int BIAS>
__global__ __launch_bounds__(256) void k_mm(const us16* __restrict__ A,
                                            const us16* __restrict__ Bt,
                                            const float* __restrict__ bias,
                                            us16* __restrict__ Cb,
                                            int M, int K, int Nc, int ny) {
  __shared__ __align__(16) us16 As[128 * 72];
  __shared__ __align__(16) us16 Bs[128 * 72];
  const int bm = (blockIdx.x / ny) * 128;
  const int bn = (blockIdx.x % ny) * 128;
  const int tid = threadIdx.x;
  const int lane = tid & 63;
  const int wave = tid >> 6;
  const int wm = (wave >> 1) * 64;
  const int wn = (wave & 1) * 64;
  const int lr = lane & 15;
  const int lk = lane >> 4;
  const int sr = tid >> 3;
  const int sc = (tid & 7) * 8;
  f32x4 acc[4][4] = {};
  for (int k0 = 0; k0 < K; k0 += 64) {
    #pragma unroll
    for (int it = 0; it < 4; ++it) {
      int r = sr + it * 32;
      int gr = bm + r;
      int4 va = make_int4(0, 0, 0, 0);
      if (gr < M) va = *(const int4*)(A + (size_t)gr * K + k0 + sc);
      *(int4*)(&As[r * 72 + sc]) = va;
      int4 vb = *(const int4*)(Bt + (size_t)(bn + r) * K + k0 + sc);
      *(int4*)(&Bs[r * 72 + sc]) = vb;
    }
    __syncthreads();
    #pragma unroll
    for (int kk = 0; kk < 2; ++kk) {
      bf16x8 af[4], bq[4];
      #pragma unroll
      for (int i = 0; i < 4; ++i)
        af[i] = *(const bf16x8*)(&As[(wm + i * 16 + lr) * 72 + kk * 32 + lk * 8]);
      #pragma unroll
      for (int j = 0; j < 4; ++j)
        bq[j] = *(const bf16x8*)(&Bs[(wn + j * 16 + lr) * 72 + kk * 32 + lk * 8]);
      #pragma unroll
      for (int i = 0; i < 4; ++i)
        #pragma unroll
        for (int j = 0; j < 4; ++j)
          acc[i][j] = __builtin_amdgcn_mfma_f32_16x16x32_bf16(af[i], bq[j], acc[i][j], 0, 0, 0);
    }
    __syncthreads();
  }
  float bb[4];
  #pragma unroll
  for (int j = 0; j < 4; ++j) bb[j] = BIAS ? bias[bn + wn + j * 16 + lr] : 0.0f;
  #pragma unroll
  for (int i = 0; i < 4; ++i) {
    #pragma unroll
    for (int q = 0; q < 4; ++q) {
      int row = bm + wm + i * 16 + lk * 4 + q;
      if (row < M) {
        #pragma unroll
        for (int j = 0; j < 4; ++j) {
          int col = bn + wn + j * 16 + lr;
          float v = acc[i][j][q] + bb[j];
          if (ACT) v = lrelu(v);
          Cb[(size_t)row * Nc + col] = f2b(v);
        }
      }
    }
  }
}

// ---------------- CSR aggregation, F=128 ----------------
template<int ACT>
__global__ __launch_bounds__(256) void k_agg128(const us16* __restrict__ hw, const int* __restrict__ rp,
                                                const int* __restrict__ csrc, const float* __restrict__ cw,
                                                const float* __restrict__ dis, const float* __restrict__ bias,
                                                us16* __restrict__ outp, int M) {
  int node = blockIdx.x * 16 + (threadIdx.x >> 4);
  int l = threadIdx.x & 15;
  if (node >= M) return;
  const us16* base = hw + l * 8;
  float acc[8], t0[8], t1[8];
  float dn = dis[node];
  float sw = dn * dn;
  {
    int4 v = *(const int4*)(base + (size_t)node * 128);
    unp8(v, t0);
    #pragma unroll
    for (int j = 0; j < 8; ++j) acc[j] = t0[j] * sw;
  }
  int e = rp[node], e1 = rp[node + 1];
  for (; e + 2 <= e1; e += 2) {
    int s0 = csrc[e], s1 = csrc[e + 1];
    float w0 = cw[e], w1 = cw[e + 1];
    int4 v0 = *(const int4*)(base + (size_t)s0 * 128);
    int4 v1 = *(const int4*)(base + (size_t)s1 * 128);
    unp8(v0, t0);
    unp8(v1, t1);
    #pragma unroll
    for (int j = 0; j < 8; ++j) acc[j] = fmaf(w0, t0[j], acc[j]);
    #pragma unroll
    for (int j = 0; j < 8; ++j) acc[j] = fmaf(w1, t1[j], acc[j]);
  }
  if (e < e1) {
    int s0 = csrc[e];
    float w0 = cw[e];
    int4 v0 = *(const int4*)(base + (size_t)s0 * 128);
    unp8(v0, t0);
    #pragma unroll
    for (int j = 0; j < 8; ++j) acc[j] = fmaf(w0, t0[j], acc[j]);
  }
  if (ACT) {
    float4 b0 = *(const float4*)(bias + l * 8);
    float4 b1 = *(const float4*)(bias + l * 8 + 4);
    float bb[8] = {b0.x, b0.y, b0.z, b0.w, b1.x, b1.y, b1.z, b1.w};
    #pragma unroll
    for (int j = 0; j < 8; ++j) acc[j] = lrelu(acc[j] + bb[j]);
  }
  int4 o;
  o.x = (int)((unsigned)f2b(acc[0]) | ((unsigned)f2b(acc[1]) << 16));
  o.y = (int)((unsigned)f2b(acc[2]) | ((unsigned)f2b(acc[3]) << 16));
  o.z = (int)((unsigned)f2b(acc[4]) | ((unsigned)f2b(acc[5]) << 16));
  o.w = (int)((unsigned)f2b(acc[6]) | ((unsigned)f2b(acc[7]) << 16));
  *(int4*)(outp + (size_t)node * 128 + l * 8) = o;
}

// ---------------- fused GRU cell (MFMA): emb = GRUCell(x, hprev) ----------------
// BM=64, BN=64, Kstep=32, 4 waves (2x2, wave tile 32x32), 6 accumulations.
// 1-D grid: bn = bid % NY (dispatch-adjacent -> L2 reuse of x/h tiles), bm = bid / NY.
template<int H, int WB, int NY>
__global__ __launch_bounds__(256) void k_fgru(const us16* __restrict__ xb, const us16* __restrict__ hb,
                                              const us16* __restrict__ Wih, const us16* __restrict__ Whh,
                                              const float* __restrict__ bih, const float* __restrict__ bhh,
                                              float* __restrict__ emb, us16* __restrict__ embb, int M) {
  constexpr int LDW = 40;
  __shared__ __align__(16) us16 xs[64 * LDW];
  __shared__ __align__(16) us16 hs[64 * LDW];
  __shared__ __align__(16) us16 ws[6][64 * LDW];
  const int bn = (blockIdx.x % NY) * 64;
  const int bm = (blockIdx.x / NY) * 64;
  const int tid = threadIdx.x;
  const int lane = tid & 63, wave = tid >> 6;
  const int wm = (wave >> 1) * 32, wn = (wave & 1) * 32;
  const int lr = lane & 15, lk = lane >> 4;
  const int srow = tid >> 2;       // 0..63
  const int scol = (tid & 3) * 8;  // 0,8,16,24
  f32x4 acc[6][2][2] = {};
  const bool rv = (bm + srow) < M;
  const us16* xrp = xb + (size_t)(bm + srow) * H;
  const us16* hrp = hb + (size_t)(bm + srow) * H;

  for (int k0 = 0; k0 < H; k0 += 32) {
    int4 vx = rv ? *(const int4*)(xrp + k0 + scol) : make_int4(0, 0, 0, 0);
    int4 vh = rv ? *(const int4*)(hrp + k0 + scol) : make_int4(0, 0, 0, 0);
    *(int4*)(xs + srow * LDW + scol) = vx;
    *(int4*)(hs + srow * LDW + scol) = vh;
    #pragma unroll
    for (int g = 0; g < 3; ++g) {
      int4 wi = *(const int4*)(Wih + (size_t)(g * H + bn + srow) * H + k0 + scol);
      *(int4*)(ws[g] + srow * LDW + scol) = wi;
      int4 wh = *(const int4*)(Whh + (size_t)(g * H + bn + srow) * H + k0 + scol);
      *(int4*)(ws[3 + g] + srow * LDW + scol) = wh;
    }
    __syncthreads();
    bf16x8 ax[2], ah[2];
    #pragma unroll
    for (int i = 0; i < 2; ++i) {
      ax[i] = *(const bf16x8*)(xs + (wm + i * 16 + lr) * LDW + lk * 8);
      ah[i] = *(const bf16x8*)(hs + (wm + i * 16 + lr) * LDW + lk * 8);
    }
    #pragma unroll
    for (int g = 0; g < 6; ++g) {
      bf16x8 bq[2];
      #pragma unroll
      for (int j = 0; j < 2; ++j)
        bq[j] = *(const bf16x8*)(ws[g] + (wn + j * 16 + lr) * LDW + lk * 8);
      #pragma unroll
      for (int i = 0; i < 2; ++i)
        #pragma unroll
        for (int j = 0; j < 2; ++j)
          acc[g][i][j] = __builtin_amdgcn_mfma_f32_16x16x32_bf16(
              (g < 3 ? ax[i] : ah[i]), bq[j], acc[g][i][j], 0, 0, 0);
    }
    __syncthreads();
  }
  // epilogue: gates (h read as bf16 — same data the gh GEMM consumed)
  #pragma unroll
  for (int j = 0; j < 2; ++j) {
    int col = bn + wn + j * 16 + lr;
    float bir = bih[col], biz = bih[H + col], bin = bih[2 * H + col];
    float bhr = bhh[col], bhz = bhh[H + col], bhn = bhh[2 * H + col];
    #pragma unroll
    for (int i = 0; i < 2; ++i) {
      #pragma unroll
      for (int q = 0; q < 4; ++q) {
        int row = bm + wm + i * 16 + lk * 4 + q;
        if (row >= M) continue;
        float r = fsigmoid(acc[0][i][j][q] + bir + acc[3][i][j][q] + bhr);
        float z = fsigmoid(acc[1][i][j][q] + biz + acc[4][i][j][q] + bhz);
        float n = ftanh(acc[2][i][j][q] + bin + r * (acc[5][i][j][q] + bhn));
        float hv = b2f(hb[(size_t)row * H + col]);
        float o = (1.0f - z) * n + z * hv;
        emb[(size_t)row * H + col] = o;
        if (WB) embb[(size_t)row * H + col] = f2b(o);
      }
    }
  }
}

// ---------------- post head: out[n] = sum_cols(emb1 @ Wpost + bpost) ----------------
__global__ __launch_bounds__(256) void k_post(const float* __restrict__ emb, const float* __restrict__ Wpost,
                                              const float* __restrict__ bpost, float* __restrict__ outv, int M) {
  int gw = (int)((blockIdx.x * 256 + threadIdx.x) >> 6);
  int lane = threadIdx.x & 63;
  if (gw >= M) return;
  float2 ev = *(const float2*)(emb + (size_t)gw * 128 + lane * 2);
  float4 wv = *(const float4*)(Wpost + lane * 4);
  float p = ev.x * (wv.x + wv.y) + ev.y * (wv.z + wv.w);
  #pragma unroll
  for (int o = 32; o > 0; o >>= 1) p += __shfl_xor(p, o);
  if (lane == 0) outv[gw] = p + bpost[0] + bpost[1];
}

extern "C" void kernel_launch(void* const* d_in, const int* in_sizes, int n_in,
                              void* d_out, int out_size, void* d_ws, size_t ws_size,
                              hipStream_t stream) {
  const float* x     = (const float*)d_in[0];
  const int*   ei    = (const int*)d_in[1];
  const float* prev0 = (const float*)d_in[2];
  const float* prev1 = (const float*)d_in[3];
  const float* Wp1   = (const float*)d_in[4];
  const float* bp1   = (const float*)d_in[5];
  const float* Wp2   = (const float*)d_in[6];
  const float* bp2   = (const float*)d_in[7];
  const float* Wc1   = (const float*)d_in[8];
  const float* bc1   = (const float*)d_in[9];
  const float* Wc2   = (const float*)d_in[10];
  const float* bc2   = (const float*)d_in[11];
  const float* Wih1  = (const float*)d_in[12];
  const float* Whh1  = (const float*)d_in[13];
  const float* bih1  = (const float*)d_in[14];
  const float* bhh1  = (const float*)d_in[15];
  const float* Wih2  = (const float*)d_in[16];
  const float* Whh2  = (const float*)d_in[17];
  const float* bih2  = (const float*)d_in[18];
  const float* bhh2  = (const float*)d_in[19];
  const float* Wpost = (const float*)d_in[20];
  const float* bpost = (const float*)d_in[21];

  const int N = in_sizes[0] / 128;   // 100000
  const int E = in_sizes[1] / 2;     // 1600000
  const int* srcp = ei;
  const int* dstp = ei + E;

  char* wsb = (char*)d_ws;
  size_t off = 0;
  auto alloc = [&](size_t bytes) -> void* {
    void* p = wsb + off;
    off = (off + bytes + 255) & ~(size_t)255;
    return p;
  };
  float* dis    = (float*)alloc((size_t)N * 4);
  int*   indeg  = (int*)alloc((size_t)N * 4);
  int*   rp     = (int*)alloc((size_t)(N + 1) * 4);
  int*   part   = (int*)alloc((size_t)1024 * 4);
  int*   cursor = (int*)alloc((size_t)N * 4);
  int*   csrc   = (int*)alloc((size_t)E * 4);
  float* cw     = (float*)alloc((size_t)E * 4);
  us16* xb    = (us16*)alloc((size_t)N * 128 * 2);
  us16* p0b   = (us16*)alloc((size_t)N * 256 * 2);
  us16* p1b   = (us16*)alloc((size_t)N * 128 * 2);
  us16* WtP1  = (us16*)alloc((size_t)256 * 128 * 2);
  us16* WtP2  = (us16*)alloc((size_t)128 * 256 * 2);
  us16* WtC1  = (us16*)alloc((size_t)256 * 128 * 2);
  us16* WtC2  = (us16*)alloc((size_t)128 * 256 * 2);
  us16* Wih1b = (us16*)alloc((size_t)768 * 256 * 2);
  us16* Whh1b = (us16*)alloc((size_t)768 * 256 * 2);
  us16* Wih2b = (us16*)alloc((size_t)384 * 128 * 2);
  us16* Whh2b = (us16*)alloc((size_t)384 * 128 * 2);
  us16* bufA  = (us16*)alloc((size_t)N * 256 * 2);  // MLP hidden / GCN1 out
  us16* bufB  = (us16*)alloc((size_t)N * 128 * 2);  // MLP out / GCN2 lin out
  us16* bufD  = (us16*)alloc((size_t)N * 128 * 2);  // agg out
  us16* emb0b = (us16*)alloc((size_t)N * 256 * 2);
  (void)ws_size; (void)n_in; (void)out_size;

  float* outv = (float*)d_out;
  float* emb0 = outv + N;
  float* emb1 = emb0 + (size_t)N * 256;

  auto cg = [](long n) { return (unsigned)((n / 4 + 255) / 256); };

  // weight/activation repack
  k_cast<<<cg((long)N * 128), 256, 0, stream>>>(x, xb, N * 128);
  k_cast<<<cg((long)N * 256), 256, 0, stream>>>(prev0, p0b, N * 256);
  k_cast<<<cg((long)N * 128), 256, 0, stream>>>(prev1, p1b, N * 128);
  k_cast<<<cg(768 * 256), 256, 0, stream>>>(Wih1, Wih1b, 768 * 256);
  k_cast<<<cg(768 * 256), 256, 0, stream>>>(Whh1, Whh1b, 768 * 256);
  k_cast<<<cg(384 * 128), 256, 0, stream>>>(Wih2, Wih2b, 384 * 128);
  k_cast<<<cg(384 * 128), 256, 0, stream>>>(Whh2, Whh2b, 384 * 128);
  k_tpose<<<(128 * 256 + 255) / 256, 256, 0, stream>>>(Wp1, WtP1, 128, 256);
  k_tpose<<<(256 * 128 + 255) / 256, 256, 0, stream>>>(Wp2, WtP2, 256, 128);
  k_tpose<<<(128 * 256 + 255) / 256, 256, 0, stream>>>(Wc1, WtC1, 128, 256);
  k_tpose<<<(256 * 128 + 255) / 256, 256, 0, stream>>>(Wc2, WtC2, 256, 128);

  // CSR build (parallel scan)
  hipMemsetAsync(indeg, 0, (size_t)N * 4, stream);
  k_deg<<<(E + 255) / 256, 256, 0, stream>>>(dstp, indeg, E);
  k_dis<<<(N + 255) / 256, 256, 0, stream>>>(indeg, dis, N);
  const int NC = (N + 1023) / 1024;  // 98
  k_scan1<<<NC, 1024, 0, stream>>>(indeg, rp, part, N);
  k_scan2<<<1, 1024, 0, stream>>>(part, NC);
  k_scan3<<<(N + 256) / 256, 256, 0, stream>>>(rp, part, N, E);
  hipMemcpyAsync(cursor, rp, (size_t)N * 4, hipMemcpyDeviceToDevice, stream);
  k_fill<<<(E + 255) / 256, 256, 0, stream>>>(srcp, dstp, dis, cursor, csrc, cw, E);

  const int MB = (N + 127) / 128;   // 782 (k_mm)
  const int FB = (N + 63) / 64;     // 1563 (k_fgru)
  const int AB = (N + 15) / 16;     // 6250 (k_agg128)

  // preprocess MLP
  k_mm<1, 1><<<MB * 2, 256, 0, stream>>>(xb, WtP1, bp1, bufA, N, 128, 256, 2);
  k_mm<1, 1><<<MB, 256, 0, stream>>>(bufA, WtP2, bp2, bufB, N, 256, 128, 1);
  // GCN1: aggregate FIRST (linearity), then linear+bias+leaky
  k_agg128<0><<<AB, 256, 0, stream>>>(bufB, rp, csrc, cw, dis, nullptr, bufD, N);
  k_mm<1, 1><<<MB * 2, 256, 0, stream>>>(bufD, WtC1, bc1, bufA, N, 128, 256, 2);
  // GRU1 fused
  k_fgru<256, 1, 4><<<FB * 4, 256, 0, stream>>>(bufA, p0b, Wih1b, Whh1b, bih1, bhh1,
                                                emb0, emb0b, N);
  // GCN2: linear first (256->128), then aggregate with bias+leaky
  k_mm<0, 0><<<MB, 256, 0, stream>>>(emb0b, WtC2, nullptr, bufB, N, 256, 128, 1);
  k_agg128<1><<<AB, 256, 0, stream>>>(bufB, rp, csrc, cw, dis, bc2, bufD, N);
  // GRU2 fused
  k_fgru<128, 0, 2><<<FB * 2, 256, 0, stream>>>(bufD, p1b, Wih2b, Whh2b, bih2, bhh2,
                                                emb1, nullptr, N);
  // post head
  k_post<<<(N + 3) / 4, 256, 0, stream>>>(emb1, Wpost, bpost, outv, N);
}